// Round 1
// baseline (7854.008 us; speedup 1.0000x reference)
//
#include <hip/hip_runtime.h>
#include <math.h>

// Problem constants (from reference)
#define B_   4096
#define D_   256
#define H_   266
#define T_   51
#define S_   50
#define HP   272        // padded row stride for H=266 buffers (16B-aligned)
#define EPSF 1e-5f

// GEMM tile config
#define BM 64
#define BN 64
#define BK 16

struct GemmJob {
  const float* A; int lda;     // A: M x K row-major
  const float* W; int ldw;     // W: K x N row-major
  const float* bias;           // N
  const float* trow;           // nullable: extra bias = tg[tidx]*trow[col]
  const float* tg; int tidx;
  float* C; int ldc;           // C: M x N row-major
  float* ssum; float* ssq;     // nullable: column stats accumulators (atomic)
  int relu;
  int K;
};

// C = A@W + bias (+ tg[tidx]*trow) [+relu], optional column sum/sumsq stats.
// Two jobs selected by blockIdx.z (must share M,N; K may differ per job).
__global__ __launch_bounds__(256) void gemm_multi(GemmJob j0, GemmJob j1, int M, int N) {
  GemmJob j = (blockIdx.z == 0) ? j0 : j1;
  __shared__ float As[BK][BM];
  __shared__ float Ws[BK][BN];
  __shared__ float red[16][BN];

  const int tid = threadIdx.x;
  const int tx = tid & 15;
  const int ty = tid >> 4;
  const int c0 = blockIdx.x * BN;
  const int r0 = blockIdx.y * BM;

  float acc[4][4];
  #pragma unroll
  for (int m = 0; m < 4; m++)
    #pragma unroll
    for (int n = 0; n < 4; n++) acc[m][n] = 0.f;

  const int arow = tid >> 2;        // 0..63
  const int akq  = (tid & 3) * 4;   // 0,4,8,12
  const int wrow = tid >> 4;        // 0..15
  const int wcq  = (tid & 15) * 4;  // 0..60

  for (int k0 = 0; k0 < j.K; k0 += BK) {
    const float* Ap = j.A + (size_t)(r0 + arow) * j.lda + k0 + akq;
    #pragma unroll
    for (int t = 0; t < 4; t++) {
      float v = 0.f;
      if (k0 + akq + t < j.K) v = Ap[t];
      As[akq + t][arow] = v;
    }
    #pragma unroll
    for (int t = 0; t < 4; t++) {
      float v = 0.f;
      int kk = k0 + wrow;
      int cc = c0 + wcq + t;
      if (kk < j.K && cc < N) v = j.W[(size_t)kk * j.ldw + cc];
      Ws[wrow][wcq + t] = v;
    }
    __syncthreads();
    #pragma unroll
    for (int kk = 0; kk < BK; kk++) {
      float a[4], w[4];
      #pragma unroll
      for (int m = 0; m < 4; m++) a[m] = As[kk][ty * 4 + m];
      #pragma unroll
      for (int n = 0; n < 4; n++) w[n] = Ws[kk][tx * 4 + n];
      #pragma unroll
      for (int m = 0; m < 4; m++)
        #pragma unroll
        for (int n = 0; n < 4; n++)
          acc[m][n] = fmaf(a[m], w[n], acc[m][n]);
    }
    __syncthreads();
  }

  float tb = 0.f;
  if (j.trow) tb = j.tg[j.tidx];

  float vals[4][4];
  #pragma unroll
  for (int m = 0; m < 4; m++) {
    int row = r0 + ty * 4 + m;
    #pragma unroll
    for (int n = 0; n < 4; n++) {
      int col = c0 + tx * 4 + n;
      float v = 0.f;
      if (col < N) {
        v = acc[m][n] + j.bias[col];
        if (j.trow) v = fmaf(tb, j.trow[col], v);
        if (j.relu) v = fmaxf(v, 0.f);
        j.C[(size_t)row * j.ldc + col] = v;
      }
      vals[m][n] = v;
    }
  }

  if (j.ssum) {
    float cs[4], cq[4];
    #pragma unroll
    for (int n = 0; n < 4; n++) {
      cs[n] = 0.f; cq[n] = 0.f;
      #pragma unroll
      for (int m = 0; m < 4; m++) { cs[n] += vals[m][n]; cq[n] += vals[m][n] * vals[m][n]; }
    }
    #pragma unroll
    for (int n = 0; n < 4; n++) red[ty][tx * 4 + n] = cs[n];
    __syncthreads();
    if (tid < BN) {
      float s = 0.f;
      #pragma unroll
      for (int t = 0; t < 16; t++) s += red[t][tid];
      if (c0 + tid < N) atomicAdd(&j.ssum[c0 + tid], s);
    }
    __syncthreads();
    #pragma unroll
    for (int n = 0; n < 4; n++) red[ty][tx * 4 + n] = cq[n];
    __syncthreads();
    if (tid < BN) {
      float s = 0.f;
      #pragma unroll
      for (int t = 0; t < 16; t++) s += red[t][tid];
      if (c0 + tid < N) atomicAdd(&j.ssq[c0 + tid], s);
    }
  }
}

// In-place batchnorm + relu over M x N (stride ld) with precomputed col stats.
__global__ __launch_bounds__(256) void bn_relu(float* h, int ld,
                                               const float* __restrict__ g,
                                               const float* __restrict__ be,
                                               const float* __restrict__ ssum,
                                               const float* __restrict__ ssq,
                                               int M, int N, float invM) {
  int total = M * N;
  for (int idx = blockIdx.x * blockDim.x + threadIdx.x; idx < total;
       idx += gridDim.x * blockDim.x) {
    int row = idx / N;
    int col = idx - row * N;
    float mu  = ssum[col] * invM;
    float var = ssq[col] * invM - mu * mu;
    float x = h[(size_t)row * ld + col];
    float y = g[col] * (x - mu) * rsqrtf(var + EPSF) + be[col];
    h[(size_t)row * ld + col] = fmaxf(y, 0.f);
  }
}

// y[r] = dot(A[r,:K], w) + b; scalar stats via atomics. One block per row.
__global__ __launch_bounds__(256) void matvec_stats(const float* __restrict__ A, int lda,
                                                    const float* __restrict__ w,
                                                    const float* __restrict__ bptr,
                                                    float* __restrict__ y,
                                                    float* ssum, float* ssq, int K) {
  int r = blockIdx.x;
  __shared__ float s[256];
  float acc = 0.f;
  for (int k = threadIdx.x; k < K; k += 256) acc += A[(size_t)r * lda + k] * w[k];
  s[threadIdx.x] = acc;
  __syncthreads();
  for (int st = 128; st > 0; st >>= 1) {
    if (threadIdx.x < st) s[threadIdx.x] += s[threadIdx.x + st];
    __syncthreads();
  }
  if (threadIdx.x == 0) {
    float v = s[0] + bptr[0];
    y[r] = v;
    atomicAdd(ssum, v);
    atomicAdd(ssq, v * v);
  }
}

__global__ __launch_bounds__(256) void v0_fin(const float* __restrict__ y, float* v,
                                              const float* g, const float* be,
                                              const float* ssum, const float* ssq,
                                              int M, float invM) {
  int r = blockIdx.x * blockDim.x + threadIdx.x;
  if (r < M) {
    float mu  = ssum[0] * invM;
    float var = ssq[0] * invM - mu * mu;
    float t = g[0] * (y[r] - mu) * rsqrtf(var + EPSF) + be[0];
    v[r] = fmaxf(t, 0.f);
  }
}

// One block (256 threads) per batch row. D = 256 = blockDim.
__global__ __launch_bounds__(256) void update_step(const float* __restrict__ xc,
                                                   float* __restrict__ xn,
                                                   const float* __restrict__ alpha,
                                                   const float* __restrict__ grad,
                                                   const float* __restrict__ xi_i,
                                                   const float* __restrict__ law_i,
                                                   const float* __restrict__ tg, int i,
                                                   float* __restrict__ v) {
  int r = blockIdx.x;
  int d = threadIdx.x;
  float hi = tg[i + 1] - tg[i];
  float sq = sqrtf(hi);  // SIGMA = 1
  size_t off = (size_t)r * D_ + d;
  float xcd = xc[off];
  float al  = alpha[off];
  float gr  = grad[off];
  float xid = xi_i[off];
  float lw  = law_i[d];
  float df  = xcd - lw;
  __shared__ float sf[256], si[256];
  sf[d] = 0.5f * (df * df + al * al);  // KAPPA = 1
  si[d] = gr * xid;
  __syncthreads();
  for (int st = 128; st > 0; st >>= 1) {
    if (d < st) { sf[d] += sf[d + st]; si[d] += si[d + st]; }
    __syncthreads();
  }
  if (d == 0) v[r] = v[r] - sf[0] * hi + sq * si[0];
  xn[off] = xcd + al * hi + sq * xid;
}

extern "C" void kernel_launch(void* const* d_in, const int* in_sizes, int n_in,
                              void* d_out, int out_size, void* d_ws, size_t ws_size,
                              hipStream_t stream) {
  const float* x    = (const float*)d_in[0];
  const float* W1   = (const float*)d_in[1];
  const float* b1   = (const float*)d_in[2];
  const float* g1   = (const float*)d_in[3];
  const float* be1  = (const float*)d_in[4];
  const float* W2   = (const float*)d_in[5];
  const float* b2   = (const float*)d_in[6];
  const float* g2   = (const float*)d_in[7];
  const float* be2  = (const float*)d_in[8];
  const float* W3   = (const float*)d_in[9];
  const float* b3   = (const float*)d_in[10];
  const float* vW1  = (const float*)d_in[11];
  const float* vb1  = (const float*)d_in[12];
  const float* vg1  = (const float*)d_in[13];
  const float* vbe1 = (const float*)d_in[14];
  const float* vW2  = (const float*)d_in[15];
  const float* vb2  = (const float*)d_in[16];
  const float* vg2  = (const float*)d_in[17];
  const float* vbe2 = (const float*)d_in[18];
  const float* vW3  = (const float*)d_in[19];
  const float* vb3  = (const float*)d_in[20];
  const float* vg3  = (const float*)d_in[21];
  const float* vbe3 = (const float*)d_in[22];
  const float* aW1  = (const float*)d_in[23];
  const float* ab1  = (const float*)d_in[24];
  const float* aW2  = (const float*)d_in[25];
  const float* ab2  = (const float*)d_in[26];
  const float* law  = (const float*)d_in[27];
  const float* tg   = (const float*)d_in[28];
  const float* xi   = (const float*)d_in[29];

  float* out    = (float*)d_out;
  float* v_out  = out;                              // B
  float* xf_out = out + B_;                         // B*D
  float* path   = out + B_ + (size_t)B_ * D_;       // T*B*D

  float* ws   = (float*)d_ws;
  float* h1   = ws;                                 // B*HP
  float* h2   = h1 + (size_t)B_ * HP;               // B*HP
  float* ah   = h2 + (size_t)B_ * HP;               // B*HP (relu(tx@aW1+ab1))
  float* grad = ah + (size_t)B_ * HP;               // B*D
  float* alp  = grad + (size_t)B_ * D_;             // B*D
  float* yraw = alp + (size_t)B_ * D_;              // B
  float* stats = yraw + B_;                         // NSLOT*2*HP

  const int NSLOT = 2 * S_ + 3;
  hipMemsetAsync(stats, 0, (size_t)NSLOT * 2 * HP * sizeof(float), stream);
  hipMemcpyAsync(path, x, (size_t)B_ * D_ * sizeof(float),
                 hipMemcpyDeviceToDevice, stream);

  auto ssum = [&](int s) { return stats + (size_t)s * 2 * HP; };
  auto ssq  = [&](int s) { return stats + (size_t)s * 2 * HP + HP; };

  dim3 blk(256);
  const float invB = 1.0f / (float)B_;

  // ---- v0 = 3-layer BN-MLP on x ----
  {
    GemmJob jv1 = {x, D_, vW1, H_, vb1, nullptr, nullptr, 0,
                   h1, HP, ssum(100), ssq(100), 0, D_};
    gemm_multi<<<dim3(5, 64, 1), blk, 0, stream>>>(jv1, jv1, B_, H_);
    bn_relu<<<dim3(1024), blk, 0, stream>>>(h1, HP, vg1, vbe1, ssum(100), ssq(100), B_, H_, invB);
    GemmJob jv2 = {h1, HP, vW2, H_, vb2, nullptr, nullptr, 0,
                   h2, HP, ssum(101), ssq(101), 0, H_};
    gemm_multi<<<dim3(5, 64, 1), blk, 0, stream>>>(jv2, jv2, B_, H_);
    bn_relu<<<dim3(1024), blk, 0, stream>>>(h2, HP, vg2, vbe2, ssum(101), ssq(101), B_, H_, invB);
    matvec_stats<<<dim3(B_), blk, 0, stream>>>(h2, HP, vW3, vb3, yraw, ssum(102), ssq(102), H_);
    v0_fin<<<dim3(16), blk, 0, stream>>>(yraw, v_out, vg3, vbe3, ssum(102), ssq(102), B_, invB);
  }

  // ---- scan over S steps; x state lives in `path` ----
  for (int i = 0; i < S_; ++i) {
    const float* xc = path + (size_t)i * B_ * D_;
    float* xn       = path + (size_t)(i + 1) * B_ * D_;

    // h1raw = xc@W1[i]+b1[i] (stats); ah = relu(xc@aW1[1:]+ti*aW1[0]+ab1)
    GemmJob ja = {xc, D_, W1 + (size_t)i * D_ * H_, H_, b1 + (size_t)i * H_,
                  nullptr, nullptr, 0, h1, HP, ssum(2 * i), ssq(2 * i), 0, D_};
    GemmJob jb = {xc, D_, aW1 + H_, H_, ab1, aW1, tg, i,
                  ah, HP, nullptr, nullptr, 1, D_};
    gemm_multi<<<dim3(5, 64, 2), blk, 0, stream>>>(ja, jb, B_, H_);

    bn_relu<<<dim3(1024), blk, 0, stream>>>(h1, HP, g1 + (size_t)i * H_, be1 + (size_t)i * H_,
                                            ssum(2 * i), ssq(2 * i), B_, H_, invB);

    GemmJob jc = {h1, HP, W2 + (size_t)i * H_ * H_, H_, b2 + (size_t)i * H_,
                  nullptr, nullptr, 0, h2, HP, ssum(2 * i + 1), ssq(2 * i + 1), 0, H_};
    gemm_multi<<<dim3(5, 64, 1), blk, 0, stream>>>(jc, jc, B_, H_);

    bn_relu<<<dim3(1024), blk, 0, stream>>>(h2, HP, g2 + (size_t)i * H_, be2 + (size_t)i * H_,
                                            ssum(2 * i + 1), ssq(2 * i + 1), B_, H_, invB);

    // grad = h2@W3[i]+b3[i]; alpha = ah@aW2+ab2
    GemmJob jd = {h2, HP, W3 + (size_t)i * H_ * D_, D_, b3 + (size_t)i * D_,
                  nullptr, nullptr, 0, grad, D_, nullptr, nullptr, 0, H_};
    GemmJob je = {ah, HP, aW2, D_, ab2,
                  nullptr, nullptr, 0, alp, D_, nullptr, nullptr, 0, H_};
    gemm_multi<<<dim3(4, 64, 2), blk, 0, stream>>>(jd, je, B_, D_);

    update_step<<<dim3(B_), blk, 0, stream>>>(xc, xn, alp, grad,
                                              xi + (size_t)i * B_ * D_,
                                              law + (size_t)i * D_, tg, i, v_out);
  }

  hipMemcpyAsync(xf_out, path + (size_t)S_ * B_ * D_,
                 (size_t)B_ * D_ * sizeof(float), hipMemcpyDeviceToDevice, stream);
}

// Round 2
// 3432.368 us; speedup vs baseline: 2.2882x; 2.2882x over previous
//
#include <hip/hip_runtime.h>
#include <math.h>

// Problem constants
#define B_   4096
#define D_   256
#define H_   266
#define T_   51
#define S_   50
#define HP   272        // padded row stride (fp32 activations)
#define EPSF 1e-5f

typedef __bf16 bf16_t;
typedef __bf16 bf16x8 __attribute__((ext_vector_type(8)));
typedef float  f32x4  __attribute__((ext_vector_type(4)));

// MFMA GEMM tile config: block 128x128, 4 waves, each wave 64x64 (4x4 MFMA tiles)
#define BM 128
#define BN 128
#define BK 32
#define LDST 40   // LDS row stride in bf16 (80 B: 16B-aligned, conflict-benign)

struct Job {
  const float* A; int lda; int Ka;                    // A: M x Ka fp32
  const float* g; const float* be;                    // BN-on-A params (bnA)
  const float* asum; const float* asq;
  int bnA;                                            // apply relu(BN(A)) while staging
  const bf16_t* Wt; int ldw;                          // Wt: N x ldw bf16, k-contig, zero-padded
  const float* bias;                                  // N
  const float* trow; const float* tg; int tidx;       // optional bias += tg[tidx]*trow[col]
  float* C; int ldc; int N; int relu;
  float* ssum; float* ssq;                            // optional column stats (atomic)
};

__global__ __launch_bounds__(256) void mfma_gemm(Job j0, Job j1, float invB) {
  Job j = blockIdx.z ? j1 : j0;
  __shared__ bf16_t As[BM][LDST];
  __shared__ bf16_t Ws[BN][LDST];
  __shared__ float sc[288], sh[288];

  const int tid = threadIdx.x;
  const int r0 = blockIdx.y * BM;
  const int c0 = blockIdx.x * BN;

  // Precompute BN scale/shift for A columns (k-dim). Zero-fill padding so
  // garbage never reaches the MFMA (pad A elems become 0).
  if (j.bnA) {
    for (int k = tid; k < 288; k += 256) {
      if (k < j.Ka) {
        float mu  = j.asum[k] * invB;
        float var = j.asq[k] * invB - mu * mu;
        float s   = j.g[k] * rsqrtf(var + EPSF);
        sc[k] = s; sh[k] = j.be[k] - mu * s;
      } else { sc[k] = 0.f; sh[k] = 0.f; }
    }
  }

  const int wave = tid >> 6;
  const int lane = tid & 63;
  const int wr = (wave >> 1) * 64;
  const int wc = (wave & 1) * 64;
  const int l16 = lane & 15;
  const int lk8 = (lane >> 4) * 8;

  f32x4 acc[4][4] = {};

  const int arow  = tid >> 1;          // 0..127
  const int akseg = (tid & 1) * 16;    // 0 or 16

  const int niter = (j.Ka + BK - 1) / BK;
  for (int it = 0; it < niter; ++it) {
    const int k0 = it * BK;

    // ---- global loads into regs ----
    float a16[16];
    const float* Ap = j.A + (size_t)(r0 + arow) * j.lda + k0 + akseg;
    if (k0 + BK <= j.Ka) {
      const float4* p = (const float4*)Ap;
      float4 v0 = p[0], v1 = p[1], v2 = p[2], v3 = p[3];
      a16[0]=v0.x; a16[1]=v0.y; a16[2]=v0.z; a16[3]=v0.w;
      a16[4]=v1.x; a16[5]=v1.y; a16[6]=v1.z; a16[7]=v1.w;
      a16[8]=v2.x; a16[9]=v2.y; a16[10]=v2.z; a16[11]=v2.w;
      a16[12]=v3.x; a16[13]=v3.y; a16[14]=v3.z; a16[15]=v3.w;
    } else {
      #pragma unroll
      for (int i = 0; i < 16; ++i) {
        int k = k0 + akseg + i;
        a16[i] = (k < j.Ka) ? Ap[i] : 0.f;
      }
    }
    uint4 wv0 = make_uint4(0,0,0,0), wv1 = make_uint4(0,0,0,0);
    {
      int cr = c0 + arow;
      if (cr < j.N) {
        const uint4* p = (const uint4*)(j.Wt + (size_t)cr * j.ldw + k0 + akseg);
        wv0 = p[0]; wv1 = p[1];
      }
    }

    __syncthreads();   // prior iter's LDS reads done (also covers sc/sh init)

    // ---- transform A + write LDS ----
    bf16x8 p0, p1;
    if (j.bnA) {
      #pragma unroll
      for (int i = 0; i < 8; ++i) {
        int k = k0 + akseg + i;
        float t = fmaxf(fmaf(a16[i], sc[k], sh[k]), 0.f);
        p0[i] = (bf16_t)t;
      }
      #pragma unroll
      for (int i = 0; i < 8; ++i) {
        int k = k0 + akseg + 8 + i;
        float t = fmaxf(fmaf(a16[8+i], sc[k], sh[k]), 0.f);
        p1[i] = (bf16_t)t;
      }
    } else {
      #pragma unroll
      for (int i = 0; i < 8; ++i) p0[i] = (bf16_t)a16[i];
      #pragma unroll
      for (int i = 0; i < 8; ++i) p1[i] = (bf16_t)a16[8+i];
    }
    *(bf16x8*)&As[arow][akseg]     = p0;
    *(bf16x8*)&As[arow][akseg + 8] = p1;
    *(uint4*)&Ws[arow][akseg]      = wv0;
    *(uint4*)&Ws[arow][akseg + 8]  = wv1;

    __syncthreads();

    // ---- fragments + MFMA ----
    bf16x8 af[4], bfr[4];
    #pragma unroll
    for (int mi = 0; mi < 4; ++mi)
      af[mi] = *(const bf16x8*)&As[wr + mi*16 + l16][lk8];
    #pragma unroll
    for (int ni = 0; ni < 4; ++ni)
      bfr[ni] = *(const bf16x8*)&Ws[wc + ni*16 + l16][lk8];
    #pragma unroll
    for (int mi = 0; mi < 4; ++mi)
      #pragma unroll
      for (int ni = 0; ni < 4; ++ni)
        acc[mi][ni] = __builtin_amdgcn_mfma_f32_16x16x32_bf16(af[mi], bfr[ni], acc[mi][ni], 0, 0, 0);
  }

  // ---- epilogue: bias (+t*trow), relu, store, column stats ----
  float tb = j.trow ? j.tg[j.tidx] : 0.f;
  float csum[4], csq[4];
  #pragma unroll
  for (int ni = 0; ni < 4; ++ni) {
    int col = c0 + wc + ni*16 + l16;
    bool cok = col < j.N;
    float bias = cok ? j.bias[col] : 0.f;
    if (j.trow && cok) bias = fmaf(tb, j.trow[col], bias);
    float s = 0.f, q = 0.f;
    #pragma unroll
    for (int mi = 0; mi < 4; ++mi) {
      #pragma unroll
      for (int r = 0; r < 4; ++r) {
        float v = acc[mi][ni][r] + bias;       // col>=N: acc==0 (W zero-padded), bias 0
        if (j.relu) v = fmaxf(v, 0.f);
        int row = r0 + wr + mi*16 + ((lane >> 4) << 2) + r;
        if (cok) j.C[(size_t)row * j.ldc + col] = v;
        s += v; q += v * v;
      }
    }
    csum[ni] = s; csq[ni] = q;
  }
  if (j.ssum) {
    #pragma unroll
    for (int ni = 0; ni < 4; ++ni) {
      float s = csum[ni], q = csq[ni];
      s += __shfl_xor(s, 16); q += __shfl_xor(q, 16);
      s += __shfl_xor(s, 32); q += __shfl_xor(q, 32);
      if (lane < 16) {
        int col = c0 + wc + ni*16 + lane;
        if (col < j.N) { atomicAdd(&j.ssum[col], s); atomicAdd(&j.ssq[col], q); }
      }
    }
  }
}

// transpose + cast: out[s][n][k] = in[s][k][n] (k<K), zero-pad to Kp
__global__ __launch_bounds__(256) void wconv(const float* __restrict__ in, bf16_t* __restrict__ out,
                                             int K, int N, int Kp, int total) {
  for (int idx = blockIdx.x * 256 + threadIdx.x; idx < total; idx += gridDim.x * 256) {
    int k = idx % Kp; int rest = idx / Kp; int n = rest % N; int s = rest / N;
    float v = (k < K) ? in[((size_t)s * K + k) * N + n] : 0.f;
    out[idx] = (bf16_t)v;
  }
}

// y[r] = sum_k relu(BN(A[r,k])) * w[k] + b ; scalar stats via atomics
__global__ __launch_bounds__(256) void matvec_bn(const float* __restrict__ A, int lda,
                                                 const float* __restrict__ g, const float* __restrict__ be,
                                                 const float* __restrict__ asum, const float* __restrict__ asq,
                                                 const float* __restrict__ w, const float* __restrict__ bptr,
                                                 float* __restrict__ y, float* ssum, float* ssq,
                                                 int K, float invB) {
  int r = blockIdx.x;
  float acc = 0.f;
  for (int k = threadIdx.x; k < K; k += 256) {
    float mu  = asum[k] * invB;
    float var = asq[k] * invB - mu * mu;
    float s   = g[k] * rsqrtf(var + EPSF);
    float val = fmaxf(fmaf(A[(size_t)r * lda + k], s, be[k] - mu * s), 0.f);
    acc += val * w[k];
  }
  __shared__ float sred[256];
  sred[threadIdx.x] = acc; __syncthreads();
  for (int st = 128; st > 0; st >>= 1) {
    if (threadIdx.x < st) sred[threadIdx.x] += sred[threadIdx.x + st];
    __syncthreads();
  }
  if (threadIdx.x == 0) {
    float v = sred[0] + bptr[0];
    y[r] = v;
    atomicAdd(ssum, v); atomicAdd(ssq, v * v);
  }
}

__global__ __launch_bounds__(256) void v0_fin(const float* __restrict__ y, float* v,
                                              const float* g, const float* be,
                                              const float* ssum, const float* ssq,
                                              int M, float invM) {
  int r = blockIdx.x * blockDim.x + threadIdx.x;
  if (r < M) {
    float mu  = ssum[0] * invM;
    float var = ssq[0] * invM - mu * mu;
    float t = g[0] * (y[r] - mu) * rsqrtf(var + EPSF) + be[0];
    v[r] = fmaxf(t, 0.f);
  }
}

__global__ __launch_bounds__(256) void update_step(const float* __restrict__ xc,
                                                   float* __restrict__ xn,
                                                   const float* __restrict__ alpha,
                                                   const float* __restrict__ grad,
                                                   const float* __restrict__ xi_i,
                                                   const float* __restrict__ law_i,
                                                   const float* __restrict__ tg, int i,
                                                   float* __restrict__ v) {
  int r = blockIdx.x;
  int d = threadIdx.x;
  float hi = tg[i + 1] - tg[i];
  float sq = sqrtf(hi);
  size_t off = (size_t)r * D_ + d;
  float xcd = xc[off];
  float al  = alpha[off];
  float gr  = grad[off];
  float xid = xi_i[off];
  float lw  = law_i[d];
  float df  = xcd - lw;
  __shared__ float sf[256], si[256];
  sf[d] = 0.5f * (df * df + al * al);
  si[d] = gr * xid;
  __syncthreads();
  for (int st = 128; st > 0; st >>= 1) {
    if (d < st) { sf[d] += sf[d + st]; si[d] += si[d + st]; }
    __syncthreads();
  }
  if (d == 0) v[r] = v[r] - sf[0] * hi + sq * si[0];
  xn[off] = xcd + al * hi + sq * xid;
}

extern "C" void kernel_launch(void* const* d_in, const int* in_sizes, int n_in,
                              void* d_out, int out_size, void* d_ws, size_t ws_size,
                              hipStream_t stream) {
  const float* x    = (const float*)d_in[0];
  const float* W1   = (const float*)d_in[1];
  const float* b1   = (const float*)d_in[2];
  const float* g1   = (const float*)d_in[3];
  const float* be1  = (const float*)d_in[4];
  const float* W2   = (const float*)d_in[5];
  const float* b2   = (const float*)d_in[6];
  const float* g2   = (const float*)d_in[7];
  const float* be2  = (const float*)d_in[8];
  const float* W3   = (const float*)d_in[9];
  const float* b3   = (const float*)d_in[10];
  const float* vW1  = (const float*)d_in[11];
  const float* vb1  = (const float*)d_in[12];
  const float* vg1  = (const float*)d_in[13];
  const float* vbe1 = (const float*)d_in[14];
  const float* vW2  = (const float*)d_in[15];
  const float* vb2  = (const float*)d_in[16];
  const float* vg2  = (const float*)d_in[17];
  const float* vbe2 = (const float*)d_in[18];
  const float* vW3  = (const float*)d_in[19];
  const float* vb3  = (const float*)d_in[20];
  const float* vg3  = (const float*)d_in[21];
  const float* vbe3 = (const float*)d_in[22];
  const float* aW1  = (const float*)d_in[23];
  const float* ab1  = (const float*)d_in[24];
  const float* aW2  = (const float*)d_in[25];
  const float* ab2  = (const float*)d_in[26];
  const float* law  = (const float*)d_in[27];
  const float* tg   = (const float*)d_in[28];
  const float* xi   = (const float*)d_in[29];

  float* out    = (float*)d_out;
  float* v_out  = out;
  float* xf_out = out + B_;
  float* path   = out + B_ + (size_t)B_ * D_;

  float* ws   = (float*)d_ws;
  float* h1   = ws;
  float* h2   = h1 + (size_t)B_ * HP;
  float* ah   = h2 + (size_t)B_ * HP;
  float* grad = ah + (size_t)B_ * HP;
  float* alp  = grad + (size_t)B_ * D_;
  float* yraw = alp + (size_t)B_ * D_;
  float* stats = yraw + B_;
  const int NSLOT = 2 * S_ + 3;

  bf16_t* wbuf = (bf16_t*)(stats + (size_t)NSLOT * 2 * HP);
  bf16_t* W1t  = wbuf;                                   // [50][266][256]
  bf16_t* W2t  = W1t + (size_t)S_ * H_ * 256;            // [50][266][272]
  bf16_t* W3t  = W2t + (size_t)S_ * H_ * 272;            // [50][256][272]
  bf16_t* aW1t = W3t + (size_t)S_ * 256 * 272;           // [266][256]
  bf16_t* aW2t = aW1t + (size_t)H_ * 256;                // [256][272]
  bf16_t* vW1t = aW2t + (size_t)256 * 272;               // [266][256]
  bf16_t* vW2t = vW1t + (size_t)H_ * 256;                // [266][272]

  hipMemsetAsync(stats, 0, (size_t)NSLOT * 2 * HP * sizeof(float), stream);
  hipMemcpyAsync(path, x, (size_t)B_ * D_ * sizeof(float), hipMemcpyDeviceToDevice, stream);

  auto ssum = [&](int s) { return stats + (size_t)s * 2 * HP; };
  auto ssq  = [&](int s) { return stats + (size_t)s * 2 * HP + HP; };

  dim3 blk(256);
  const float invB = 1.0f / (float)B_;

  // ---- one-time (per launch) weight transpose+cast ----
  wconv<<<dim3(1024), blk, 0, stream>>>(W1,        W1t,  256, H_, 256, S_ * H_ * 256);
  wconv<<<dim3(1024), blk, 0, stream>>>(W2,        W2t,  H_,  H_, 272, S_ * H_ * 272);
  wconv<<<dim3(1024), blk, 0, stream>>>(W3,        W3t,  H_,  256, 272, S_ * 256 * 272);
  wconv<<<dim3(256),  blk, 0, stream>>>(aW1 + H_,  aW1t, 256, H_, 256, H_ * 256);
  wconv<<<dim3(256),  blk, 0, stream>>>(aW2,       aW2t, H_,  256, 272, 256 * 272);
  wconv<<<dim3(256),  blk, 0, stream>>>(vW1,       vW1t, 256, H_, 256, H_ * 256);
  wconv<<<dim3(256),  blk, 0, stream>>>(vW2,       vW2t, H_,  H_, 272, H_ * 272);

  // ---- v0 = 3-layer BN-MLP on x ----
  {
    Job jv1 = {x, D_, D_, nullptr, nullptr, nullptr, nullptr, 0,
               vW1t, 256, vb1, nullptr, nullptr, 0,
               h1, HP, H_, 0, ssum(100), ssq(100)};
    mfma_gemm<<<dim3(3, 32, 1), blk, 0, stream>>>(jv1, jv1, invB);
    Job jv2 = {h1, HP, H_, vg1, vbe1, ssum(100), ssq(100), 1,
               vW2t, 272, vb2, nullptr, nullptr, 0,
               h2, HP, H_, 0, ssum(101), ssq(101)};
    mfma_gemm<<<dim3(3, 32, 1), blk, 0, stream>>>(jv2, jv2, invB);
    matvec_bn<<<dim3(B_), blk, 0, stream>>>(h2, HP, vg2, vbe2, ssum(101), ssq(101),
                                            vW3, vb3, yraw, ssum(102), ssq(102), H_, invB);
    v0_fin<<<dim3(16), blk, 0, stream>>>(yraw, v_out, vg3, vbe3, ssum(102), ssq(102), B_, invB);
  }

  // ---- scan ----
  for (int i = 0; i < S_; ++i) {
    const float* xc = path + (size_t)i * B_ * D_;
    float* xn       = path + (size_t)(i + 1) * B_ * D_;

    Job ja = {xc, D_, D_, nullptr, nullptr, nullptr, nullptr, 0,
              W1t + (size_t)i * H_ * 256, 256, b1 + (size_t)i * H_, nullptr, nullptr, 0,
              h1, HP, H_, 0, ssum(2 * i), ssq(2 * i)};
    Job jb = {xc, D_, D_, nullptr, nullptr, nullptr, nullptr, 0,
              aW1t, 256, ab1, aW1, tg, i,
              ah, HP, H_, 1, nullptr, nullptr};
    mfma_gemm<<<dim3(3, 32, 2), blk, 0, stream>>>(ja, jb, invB);

    Job jc = {h1, HP, H_, g1 + (size_t)i * H_, be1 + (size_t)i * H_, ssum(2 * i), ssq(2 * i), 1,
              W2t + (size_t)i * H_ * 272, 272, b2 + (size_t)i * H_, nullptr, nullptr, 0,
              h2, HP, H_, 0, ssum(2 * i + 1), ssq(2 * i + 1)};
    mfma_gemm<<<dim3(3, 32, 1), blk, 0, stream>>>(jc, jc, invB);

    Job jd = {h2, HP, H_, g2 + (size_t)i * H_, be2 + (size_t)i * H_, ssum(2 * i + 1), ssq(2 * i + 1), 1,
              W3t + (size_t)i * 256 * 272, 272, b3 + (size_t)i * D_, nullptr, nullptr, 0,
              grad, D_, D_, 0, nullptr, nullptr};
    Job je = {ah, HP, H_, nullptr, nullptr, nullptr, nullptr, 0,
              aW2t, 272, ab2, nullptr, nullptr, 0,
              alp, D_, D_, 0, nullptr, nullptr};
    mfma_gemm<<<dim3(2, 32, 2), blk, 0, stream>>>(jd, je, invB);

    update_step<<<dim3(B_), blk, 0, stream>>>(xc, xn, alp, grad,
                                              xi + (size_t)i * B_ * D_,
                                              law + (size_t)i * D_, tg, i, v_out);
  }

  hipMemcpyAsync(xf_out, path + (size_t)S_ * B_ * D_,
                 (size_t)B_ * D_ * sizeof(float), hipMemcpyDeviceToDevice, stream);
}